// Round 16
// baseline (423.151 us; speedup 1.0000x reference)
//
#include <hip/hip_runtime.h>

#define S_  512
#define F_  64
#define GQ  128   // 4*H
#define ZR  36    // z plane row stride (floats)
#define HR  40    // h plane row stride (ushorts)

typedef __attribute__((ext_vector_type(8))) short bf16x8;
typedef __attribute__((ext_vector_type(4))) float f32x4;

// f32 -> (bf16_hi << 16) | bf16_lo, both RNE
__device__ __forceinline__ unsigned pack_split(float f) {
    unsigned u  = __builtin_bit_cast(unsigned, f);
    unsigned hi = (u + 0x7FFFu + ((u >> 16) & 1u)) & 0xFFFF0000u;
    float    fl = f - __builtin_bit_cast(float, hi);
    unsigned ul = __builtin_bit_cast(unsigned, fl);
    unsigned lo = (ul + 0x7FFFu + ((ul >> 16) & 1u)) >> 16;
    return hi | lo;
}

// f32 -> bf16 (RNE)
__device__ __forceinline__ unsigned short bf16_rne(float f) {
    unsigned u = __builtin_bit_cast(unsigned, f);
    return (unsigned short)((u + 0x7FFFu + ((u >> 16) & 1u)) >> 16);
}

__device__ __forceinline__ float sigm(float z) {
    return __builtin_amdgcn_rcpf(1.0f + __expf(-z));
}
__device__ __forceinline__ float tanh_f(float z) {
    return 2.0f * __builtin_amdgcn_rcpf(1.0f + __expf(-2.0f * z)) - 1.0f;
}

#define MFMA(A, B, C) __builtin_amdgcn_mfma_f32_16x16x32_bf16(A, B, C, 0, 0, 0)

struct X8 { float4 a, b; };

__device__ __forceinline__ bf16x8 cvt8(const X8& v) {
    bf16x8 r;
    r[0] = (short)bf16_rne(v.a.x); r[1] = (short)bf16_rne(v.a.y);
    r[2] = (short)bf16_rne(v.a.z); r[3] = (short)bf16_rne(v.a.w);
    r[4] = (short)bf16_rne(v.b.x); r[5] = (short)bf16_rne(v.b.y);
    r[6] = (short)bf16_rne(v.b.z); r[7] = (short)bf16_rne(v.b.w);
    return r;
}

// One fully-independent wave per block, 2 batch elements per wave.
// Transposed MFMA: A = weight cols (regs, 8 tiles of 16 gates), B = x/h (regs/LDS).
// Tile m covers gate cols 16m..16m+15; lane (c16,kg) holds D rows 4kg+r, col c16
// -> gate 16m+4kg+r of batch c16 (c16<2 real). z spread via intra-wave LDS plane
// (no barriers needed beyond 1-wave syncthreads); combine 1 cell/lane.
__global__ __launch_bounds__(64, 1)
void lstm_wave_kernel(const float* __restrict__ x,  const float* __restrict__ Wx,
                      const float* __restrict__ Wh, const float* __restrict__ bg,
                      const float* __restrict__ W1, const float* __restrict__ b1,
                      const float* __restrict__ W2, const float* __restrict__ b2,
                      const float* __restrict__ Wo, const float* __restrict__ bo,
                      float* __restrict__ out)
{
    const int L   = threadIdx.x;     // 0..63
    const int c16 = L & 15;          // A row (gate-in-tile) / D col (batch)
    const int kg  = L >> 4;          // k-group
    const size_t b0 = (size_t)blockIdx.x * 2;

    __shared__ __align__(16) float zp[8][ZR];            // [batch*4+G][unit]
    __shared__ __align__(16) unsigned short hp[2][HR];   // h bf16 [batch][unit]
    __shared__ float Hh[2][36], Ha[2][36];               // head buffers

    // ---- A-fragments: weight columns gc = 16m + c16, split hi/lo ----
    bf16x8 wxh[8][2], wxl[8][2], whh[8], whl[8];
    f32x4 bias[8];
#pragma unroll
    for (int m = 0; m < 8; ++m) {
        const int gc = 16 * m + c16;
#pragma unroll
        for (int c = 0; c < 2; ++c)
#pragma unroll
            for (int i = 0; i < 8; ++i) {
                unsigned p = pack_split(Wx[(size_t)(32 * c + 8 * kg + i) * GQ + gc]);
                wxh[m][c][i] = (short)(unsigned short)(p >> 16);
                wxl[m][c][i] = (short)(unsigned short)(p & 0xFFFFu);
            }
#pragma unroll
        for (int i = 0; i < 8; ++i) {
            unsigned p = pack_split(Wh[(size_t)(8 * kg + i) * GQ + gc]);
            whh[m][i] = (short)(unsigned short)(p >> 16);
            whl[m][i] = (short)(unsigned short)(p & 0xFFFFu);
        }
#pragma unroll
        for (int r = 0; r < 4; ++r) bias[m][r] = bg[16 * m + 4 * kg + r];
    }

    // x source for this lane's B-column (batch c16&1), feature base 8*kg
    const float* xb = x + (b0 + (size_t)(c16 & 1)) * (S_ * F_);
    const int f0 = 8 * kg;

    // prologue: t=0 floats (convert now), t=1 floats (in flight)
    X8 xc0, xc1, xn0, xn1;
    xc0.a = *(const float4*)(xb + f0);          xc0.b = *(const float4*)(xb + f0 + 4);
    xc1.a = *(const float4*)(xb + 32 + f0);     xc1.b = *(const float4*)(xb + 32 + f0 + 4);
    xn0.a = *(const float4*)(xb + F_ + f0);     xn0.b = *(const float4*)(xb + F_ + f0 + 4);
    xn1.a = *(const float4*)(xb + F_ + 32 + f0); xn1.b = *(const float4*)(xb + F_ + 32 + f0 + 4);

    bf16x8 bx0 = cvt8(xc0), bx1 = cvt8(xc1);
    bf16x8 bh = (bf16x8){0, 0, 0, 0, 0, 0, 0, 0};   // h_{-1} = 0

    const int bl = L >> 5, ul = L & 31;   // combine cell: batch bl, unit ul
    float cc = 0.0f, hv = 0.0f;

    for (int t = 0; t < S_; ++t) {
        // issue x loads for t+2 (2 steps of latency cover)
        int tl = t + 2; if (tl > S_ - 1) tl = S_ - 1;
        X8 nf0, nf1;
        nf0.a = *(const float4*)(xb + (size_t)tl * F_ + f0);
        nf0.b = *(const float4*)(xb + (size_t)tl * F_ + f0 + 4);
        nf1.a = *(const float4*)(xb + (size_t)tl * F_ + 32 + f0);
        nf1.b = *(const float4*)(xb + (size_t)tl * F_ + 32 + f0 + 4);

        // 8 gate tiles x 6 MFMAs (bias + 4 x-terms + 2 h-terms), then z-spread
#pragma unroll
        for (int m = 0; m < 8; ++m) {
            f32x4 a = MFMA(wxh[m][0], bx0, bias[m]);
            a = MFMA(wxh[m][1], bx1, a);
            a = MFMA(wxl[m][0], bx0, a);
            a = MFMA(wxl[m][1], bx1, a);
            a = MFMA(whh[m], bh, a);
            a = MFMA(whl[m], bh, a);
            if (c16 < 2)
                *(f32x4*)&zp[(c16 << 2) + (m >> 1)][16 * (m & 1) + 4 * kg] = a;
        }
        __syncthreads();   // 1-wave: lgkm drain + trivial barrier

        // combine: one (batch, unit) cell per lane
        float zi = zp[(bl << 2) + 0][ul];
        float zf = zp[(bl << 2) + 1][ul];
        float zg = zp[(bl << 2) + 2][ul];
        float zo = zp[(bl << 2) + 3][ul];
        float iv = sigm(zi), fv = sigm(zf);
        float gv = tanh_f(zg), ov = sigm(zo);
        cc = fmaf(fv, cc, iv * gv);
        hv = ov * tanh_f(cc);
        hp[bl][ul] = bf16_rne(hv);

        // convert x(t+1) -> frags; rotate prefetch registers
        bx0 = cvt8(xn0); bx1 = cvt8(xn1);
        xn0 = nf0; xn1 = nf1;
        __syncthreads();

        // h fragment for next step: units 8kg..8kg+7 of this col's batch
        bh = *(const bf16x8*)&hp[c16 & 1][8 * kg];
    }

    // ---- MLP head: 32 -> 32 -> 16 -> 3, leaky_relu(0.01) ----
    Hh[bl][ul] = hv;
    __syncthreads();
    {
        float a = b1[ul];
#pragma unroll
        for (int k = 0; k < 32; ++k) a = fmaf(Hh[bl][k], W1[k * 32 + ul], a);
        a = (a > 0.0f) ? a : 0.01f * a;
        Ha[bl][ul] = a;
    }
    __syncthreads();
    if (L < 32) {
        int rb = L >> 4, n = L & 15;
        float a = b2[n];
#pragma unroll
        for (int k = 0; k < 32; ++k) a = fmaf(Ha[rb][k], W2[k * 16 + n], a);
        a = (a > 0.0f) ? a : 0.01f * a;
        Hh[rb][n] = a;   // reuse
    }
    __syncthreads();
    if (L < 6) {
        int rb = L / 3, n = L - rb * 3;
        float a = bo[n];
#pragma unroll
        for (int k = 0; k < 16; ++k) a = fmaf(Hh[rb][k], Wo[k * 3 + n], a);
        out[(b0 + rb) * 3 + n] = a;
    }
}

extern "C" void kernel_launch(void* const* d_in, const int* in_sizes, int n_in,
                              void* d_out, int out_size, void* d_ws, size_t ws_size,
                              hipStream_t stream) {
    const float* x  = (const float*)d_in[0];
    const float* Wx = (const float*)d_in[1];
    const float* Wh = (const float*)d_in[2];
    const float* bg = (const float*)d_in[3];
    const float* W1 = (const float*)d_in[4];
    const float* b1 = (const float*)d_in[5];
    const float* W2 = (const float*)d_in[6];
    const float* b2 = (const float*)d_in[7];
    const float* Wo = (const float*)d_in[8];
    const float* bo = (const float*)d_in[9];
    float* out = (float*)d_out;

    hipLaunchKernelGGL(lstm_wave_kernel, dim3(1024), dim3(64), 0, stream,
                       x, Wx, Wh, bg, W1, b1, W2, b2, Wo, bo, out);
}

// Round 17
// 155.810 us; speedup vs baseline: 2.7158x; 2.7158x over previous
//
#include <hip/hip_runtime.h>

#define S_  512
#define F_  64
#define H_  32
#define GQ  128   // 4*H
#define BT  8     // real batch rows per block
#define NB  256   // 2048/BT -> one block per CU

#define XS  72    // x plane row stride (ushorts)
#define HS  40    // h plane row stride (ushorts)
#define GS  33    // head buffer row stride (floats)

typedef __attribute__((ext_vector_type(8))) short bf16x8;
typedef __attribute__((ext_vector_type(4))) float f32x4;

// f32 -> (bf16_hi << 16) | bf16_lo, both RNE
__device__ __forceinline__ unsigned pack_split(float f) {
    unsigned u  = __builtin_bit_cast(unsigned, f);
    unsigned hi = (u + 0x7FFFu + ((u >> 16) & 1u)) & 0xFFFF0000u;
    float    fl = f - __builtin_bit_cast(float, hi);
    unsigned ul = __builtin_bit_cast(unsigned, fl);
    unsigned lo = (ul + 0x7FFFu + ((ul >> 16) & 1u)) >> 16;
    return hi | lo;
}

// f32 -> bf16 (RNE)
__device__ __forceinline__ unsigned short bf16_rne(float f) {
    unsigned u = __builtin_bit_cast(unsigned, f);
    return (unsigned short)((u + 0x7FFFu + ((u >> 16) & 1u)) >> 16);
}

__device__ __forceinline__ float sigm(float z) {
    return __builtin_amdgcn_rcpf(1.0f + __expf(-z));
}
__device__ __forceinline__ float tanh_f(float z) {
    return 2.0f * __builtin_amdgcn_rcpf(1.0f + __expf(-2.0f * z)) - 1.0f;
}

#define MFMA(A, B, C) __builtin_amdgcn_mfma_f32_16x16x32_bf16(A, B, C, 0, 0, 0)

// 8 waves, BT=8, one block/CU. Transposed MFMA, time-packed (col = batch + 8*dt).
// R17: h-part is a SINGLE MFMA (Wh-lo term dropped; h is bf16 anyway);
// g-gate columns pre-scaled x2 (tanh fold); x-stage write hoisted to DSTEP top
// so both barriers drain an empty lgkm queue. Everything else = R13 (170 us).
__global__ __launch_bounds__(512, 1)
void lstm_mfma_kernel(const float* __restrict__ x,  const float* __restrict__ Wx,
                      const float* __restrict__ Wh, const float* __restrict__ bg,
                      const float* __restrict__ W1, const float* __restrict__ b1,
                      const float* __restrict__ W2, const float* __restrict__ b2,
                      const float* __restrict__ Wo, const float* __restrict__ bo,
                      float* __restrict__ out)
{
    const int tid = threadIdx.x;     // 0..511
    const int w   = tid >> 6;        // wave id 0..7
    const int L   = tid & 63;
    const int c16 = L & 15;          // B col: batch(0..7) + 8*dt / D col
    const int kg  = L >> 4;          // k-group AND unit-offset of D rows
    const int bb  = blockIdx.x * BT;
    const int jj  = (w << 2) + kg;   // hidden unit owned by this lane

    // A row m=c16 -> weight column; gate = c16&3 (g-gate scaled x2)
    const int gcol = ((c16 & 3) << 5) + (w << 2) + (c16 >> 2);
    const float gsc = ((c16 & 3) == 2) ? 2.0f : 1.0f;

    __shared__ __align__(16) unsigned short xh[4][16][XS];   // x hi-plane ring
    __shared__ __align__(16) unsigned short hh[2][16][HS];   // h hi-plane, parity
    __shared__ float Hd[3][BT][GS];

    // ---- register-resident weights ----
    bf16x8 whh_, wx0h, wx0l, wx1h, wx1l;
#pragma unroll
    for (int i = 0; i < 8; ++i) {
        unsigned p = pack_split(Wx[(kg * 8 + i) * GQ + gcol] * gsc);
        wx0h[i] = (short)(unsigned short)(p >> 16);
        wx0l[i] = (short)(unsigned short)(p & 0xFFFFu);
        p = pack_split(Wx[(32 + kg * 8 + i) * GQ + gcol] * gsc);
        wx1h[i] = (short)(unsigned short)(p >> 16);
        wx1l[i] = (short)(unsigned short)(p & 0xFFFFu);
        whh_[i] = (short)bf16_rne(Wh[(kg * 8 + i) * GQ + gcol] * gsc);
    }
    f32x4 biasC;
#pragma unroll
    for (int r = 0; r < 4; ++r) biasC[r] = bg[r * 32 + jj] * ((r == 2) ? 2.0f : 1.0f);
    const f32x4 zeroC = {0.f, 0.f, 0.f, 0.f};

    // ---- zero h planes (rows 8..15 stay zero forever) ----
    for (int i = tid; i < 2 * 16 * (HS / 2); i += 512)
        ((unsigned*)&hh[0][0][0])[i] = 0u;

    // staging map: row = batch(0..7) + 8*dt, feature pair; 1 u32 write per lane
    const int srow = tid >> 5;       // 0..15
    const int sfp  = tid & 31;       // feature pair
    const int sdt  = srow >> 3;      // dt 0/1
    const float* xsrc = x + (size_t)(bb + (srow & 7)) * S_ * F_ + 2 * sfp;
    {
#pragma unroll
        for (int tt = 0; tt < 2; ++tt) {
            float2 v = *(const float2*)(xsrc + (size_t)(2 * tt + sdt) * F_);
            *(unsigned*)&xh[tt][srow][2 * sfp] =
                (unsigned)bf16_rne(v.x) | ((unsigned)bf16_rne(v.y) << 16);
        }
    }
    float2 xvA = *(const float2*)(xsrc + (size_t)(4 + sdt) * F_);   // slot 2
    float2 xvB = *(const float2*)(xsrc + (size_t)(6 + sdt) * F_);   // slot 3
    __syncthreads();

    // initial XGEMM (td=0) from slot 0 -> registers
    f32x4 xzA, xz1s;
    {
        bf16x8 bxh0 = *(const bf16x8*)&xh[0][c16][kg * 8];
        bf16x8 bxh1 = *(const bf16x8*)&xh[0][c16][32 + kg * 8];
        f32x4 b0 = MFMA(wx0h, bxh0, biasC);
        f32x4 b2 = MFMA(wx0l, bxh0, zeroC);
        b0 = MFMA(wx1h, bxh1, b0);
        b2 = MFMA(wx1l, bxh1, b2);
        f32x4 xs = b0 + b2;
        xzA = xs;
#pragma unroll
        for (int r = 0; r < 4; ++r) xz1s[r] = __shfl_xor(xs[r], 8);
    }

    float cc = 0.0f;

#define DSTEP(TD, XV) {                                                        \
    const int td = (TD);                                                       \
    /* stage slot td+2 from XV at TOP (lgkm queue empty at both barriers) */   \
    *(unsigned*)&xh[(td + 2) & 3][srow][2 * sfp] =                             \
        (unsigned)bf16_rne(XV.x) | ((unsigned)bf16_rne(XV.y) << 16);           \
    int tl = td + 4; if (tl > 255) tl = 255;                                   \
    float2 xnext = *(const float2*)(xsrc + (size_t)(2 * tl + sdt) * F_);       \
    /* phase 1: rec step 2td (h[2td-1] in plane 1) */                          \
    bf16x8 bhh = *(const bf16x8*)&hh[1][c16][kg * 8];                          \
    f32x4 z = MFMA(whh_, bhh, xzA);                                            \
    float iv = sigm(z[0]), fv = sigm(z[1]);                                    \
    float gv = 2.0f * sigm(z[2]) - 1.0f, ov = sigm(z[3]);                      \
    cc = fmaf(fv, cc, iv * gv);                                                \
    float hv = ov * tanh_f(cc);                                                \
    if (c16 < 8) hh[0][c16][jj] = bf16_rne(hv);                                \
    /* XGEMM(td+1) from slot (td+1)&3 -> next regs (independent of h) */       \
    f32x4 xzA_n, xz1s_n;                                                       \
    {                                                                          \
        const int s1 = (td + 1) & 3;                                           \
        bf16x8 bxh0 = *(const bf16x8*)&xh[s1][c16][kg * 8];                    \
        bf16x8 bxh1 = *(const bf16x8*)&xh[s1][c16][32 + kg * 8];               \
        f32x4 b0 = MFMA(wx0h, bxh0, biasC);                                    \
        f32x4 b2 = MFMA(wx0l, bxh0, zeroC);                                    \
        b0 = MFMA(wx1h, bxh1, b0);                                             \
        b2 = MFMA(wx1l, bxh1, b2);                                             \
        f32x4 xs = b0 + b2;                                                    \
        xzA_n = xs;                                                            \
        _Pragma("unroll")                                                      \
        for (int r = 0; r < 4; ++r) xz1s_n[r] = __shfl_xor(xs[r], 8);          \
    }                                                                          \
    __syncthreads();   /* A: h[2td] visible */                                 \
    /* phase 2: rec step 2td+1 (h[2td] in plane 0) */                          \
    bhh = *(const bf16x8*)&hh[0][c16][kg * 8];                                 \
    z = MFMA(whh_, bhh, xz1s);                                                 \
    iv = sigm(z[0]); fv = sigm(z[1]);                                          \
    gv = 2.0f * sigm(z[2]) - 1.0f; ov = sigm(z[3]);                            \
    cc = fmaf(fv, cc, iv * gv);                                                \
    hv = ov * tanh_f(cc);                                                      \
    if (c16 < 8) {                                                             \
        hh[1][c16][jj] = bf16_rne(hv);                                         \
        if (td == 255) Hd[0][c16][jj] = hv;                                    \
    }                                                                          \
    XV = xnext;                                                                \
    xzA = xzA_n; xz1s = xz1s_n;                                                \
    __syncthreads();   /* B: h[2td+1] + slot td+2 visible */                   \
}

    for (int qd = 0; qd < 128; ++qd) {
        DSTEP(2 * qd,     xvA)
        DSTEP(2 * qd + 1, xvB)
    }
#undef DSTEP

    __syncthreads();

    // ---- MLP head: 32 -> 32 -> 16 -> 3, leaky_relu(0.01) ----
    if (tid < 256) {
        int rb = tid >> 5, n = tid & 31;
        float a = b1[n];
#pragma unroll
        for (int k = 0; k < 32; ++k) a = fmaf(Hd[0][rb][k], W1[k * 32 + n], a);
        a = (a > 0.0f) ? a : 0.01f * a;
        Hd[1][rb][n] = a;
    }
    __syncthreads();
    if (tid < 128) {
        int rb = tid >> 4, n = tid & 15;
        float a = b2[n];
#pragma unroll
        for (int k = 0; k < 32; ++k) a = fmaf(Hd[1][rb][k], W2[k * 16 + n], a);
        a = (a > 0.0f) ? a : 0.01f * a;
        Hd[2][rb][n] = a;
    }
    __syncthreads();
    if (tid < 24) {
        int rb = tid / 3, n = tid - rb * 3;
        float a = bo[n];
#pragma unroll
        for (int k = 0; k < 16; ++k) a = fmaf(Hd[2][rb][k], Wo[k * 3 + n], a);
        out[(size_t)(bb + rb) * 3 + n] = a;
    }
}

extern "C" void kernel_launch(void* const* d_in, const int* in_sizes, int n_in,
                              void* d_out, int out_size, void* d_ws, size_t ws_size,
                              hipStream_t stream) {
    const float* x  = (const float*)d_in[0];
    const float* Wx = (const float*)d_in[1];
    const float* Wh = (const float*)d_in[2];
    const float* bg = (const float*)d_in[3];
    const float* W1 = (const float*)d_in[4];
    const float* b1 = (const float*)d_in[5];
    const float* W2 = (const float*)d_in[6];
    const float* b2 = (const float*)d_in[7];
    const float* Wo = (const float*)d_in[8];
    const float* bo = (const float*)d_in[9];
    float* out = (float*)d_out;

    hipLaunchKernelGGL(lstm_mfma_kernel, dim3(NB), dim3(512), 0, stream,
                       x, Wx, Wh, bg, W1, b1, W2, b2, Wo, bo, out);
}

// Round 18
// 146.289 us; speedup vs baseline: 2.8926x; 1.0651x over previous
//
#include <hip/hip_runtime.h>

#define S_  512
#define F_  64
#define H_  32
#define GQ  128   // 4*H
#define BT  8     // real batch rows per block
#define NB  256   // 2048/BT -> one block per CU

#define XS  72    // x plane row stride (ushorts)
#define HS  40    // h plane row stride (ushorts)
#define GS  33    // head buffer row stride (floats)

typedef __attribute__((ext_vector_type(8))) short bf16x8;
typedef __attribute__((ext_vector_type(4))) float f32x4;

// f32 -> bf16 (RNE)
__device__ __forceinline__ unsigned short bf16_rne(float f) {
    unsigned u = __builtin_bit_cast(unsigned, f);
    return (unsigned short)((u + 0x7FFFu + ((u >> 16) & 1u)) >> 16);
}

__device__ __forceinline__ float sigm(float z) {
    return __builtin_amdgcn_rcpf(1.0f + __expf(-z));
}
__device__ __forceinline__ float tanh_f(float z) {
    return 2.0f * __builtin_amdgcn_rcpf(1.0f + __expf(-2.0f * z)) - 1.0f;
}

#define MFMA(A, B, C) __builtin_amdgcn_mfma_f32_16x16x32_bf16(A, B, C, 0, 0, 0)

// 8 waves, BT=8, one block/CU. Transposed MFMA, time-packed (col = batch + 8*dt).
// R18: all weights pure bf16 (lo-terms dropped; h/x are bf16 anyway).
// XGEMM(td+1) = 2 MFMAs, SPLIT one per phase so phase 2's h-read latency is
// covered: part in phase-1 shadow, completion + shuffles in phase-2 shadow.
__global__ __launch_bounds__(512, 1)
void lstm_mfma_kernel(const float* __restrict__ x,  const float* __restrict__ Wx,
                      const float* __restrict__ Wh, const float* __restrict__ bg,
                      const float* __restrict__ W1, const float* __restrict__ b1,
                      const float* __restrict__ W2, const float* __restrict__ b2,
                      const float* __restrict__ Wo, const float* __restrict__ bo,
                      float* __restrict__ out)
{
    const int tid = threadIdx.x;     // 0..511
    const int w   = tid >> 6;        // wave id 0..7
    const int L   = tid & 63;
    const int c16 = L & 15;          // B col: batch(0..7) + 8*dt / D col
    const int kg  = L >> 4;          // k-group AND unit-offset of D rows
    const int bb  = blockIdx.x * BT;
    const int jj  = (w << 2) + kg;   // hidden unit owned by this lane

    // A row m=c16 -> weight column; gate = c16&3 (g-gate scaled x2, tanh fold)
    const int gcol = ((c16 & 3) << 5) + (w << 2) + (c16 >> 2);
    const float gsc = ((c16 & 3) == 2) ? 2.0f : 1.0f;

    __shared__ __align__(16) unsigned short xh[4][16][XS];   // x hi-plane ring
    __shared__ __align__(16) unsigned short hh[2][16][HS];   // h hi-plane, parity
    __shared__ float Hd[3][BT][GS];

    // ---- register-resident weights (pure bf16) ----
    bf16x8 whh_, wx0h, wx1h;
#pragma unroll
    for (int i = 0; i < 8; ++i) {
        wx0h[i] = (short)bf16_rne(Wx[(kg * 8 + i) * GQ + gcol] * gsc);
        wx1h[i] = (short)bf16_rne(Wx[(32 + kg * 8 + i) * GQ + gcol] * gsc);
        whh_[i] = (short)bf16_rne(Wh[(kg * 8 + i) * GQ + gcol] * gsc);
    }
    f32x4 biasC;
#pragma unroll
    for (int r = 0; r < 4; ++r) biasC[r] = bg[r * 32 + jj] * ((r == 2) ? 2.0f : 1.0f);

    // ---- zero h planes (rows 8..15 stay zero forever) ----
    for (int i = tid; i < 2 * 16 * (HS / 2); i += 512)
        ((unsigned*)&hh[0][0][0])[i] = 0u;

    // staging map: row = batch(0..7) + 8*dt, feature pair; 1 u32 write per lane
    const int srow = tid >> 5;       // 0..15
    const int sfp  = tid & 31;       // feature pair
    const int sdt  = srow >> 3;      // dt 0/1
    const float* xsrc = x + (size_t)(bb + (srow & 7)) * S_ * F_ + 2 * sfp;
    {
#pragma unroll
        for (int tt = 0; tt < 2; ++tt) {
            float2 v = *(const float2*)(xsrc + (size_t)(2 * tt + sdt) * F_);
            *(unsigned*)&xh[tt][srow][2 * sfp] =
                (unsigned)bf16_rne(v.x) | ((unsigned)bf16_rne(v.y) << 16);
        }
    }
    float2 xvA = *(const float2*)(xsrc + (size_t)(4 + sdt) * F_);   // slot 2
    float2 xvB = *(const float2*)(xsrc + (size_t)(6 + sdt) * F_);   // slot 3
    __syncthreads();

    // initial XGEMM (td=0) from slot 0 -> registers
    f32x4 xzA, xz1s;
    {
        bf16x8 bxh0 = *(const bf16x8*)&xh[0][c16][kg * 8];
        bf16x8 bxh1 = *(const bf16x8*)&xh[0][c16][32 + kg * 8];
        f32x4 b0 = MFMA(wx0h, bxh0, biasC);
        f32x4 xs = MFMA(wx1h, bxh1, b0);
        xzA = xs;
#pragma unroll
        for (int r = 0; r < 4; ++r) xz1s[r] = __shfl_xor(xs[r], 8);
    }

    float cc = 0.0f;

#define DSTEP(TD, XV) {                                                        \
    const int td = (TD);                                                       \
    /* stage slot td+2 at TOP (queue empty by the time barriers hit) */        \
    *(unsigned*)&xh[(td + 2) & 3][srow][2 * sfp] =                             \
        (unsigned)bf16_rne(XV.x) | ((unsigned)bf16_rne(XV.y) << 16);           \
    int tl = td + 4; if (tl > 255) tl = 255;                                   \
    float2 xnext = *(const float2*)(xsrc + (size_t)(2 * tl + sdt) * F_);       \
    const int s1 = (td + 1) & 3;                                               \
    /* phase 1: rec step 2td (h[2td-1] in plane 1) + XGEMM first half */       \
    bf16x8 bxh0 = *(const bf16x8*)&xh[s1][c16][kg * 8];                        \
    bf16x8 bhh1 = *(const bf16x8*)&hh[1][c16][kg * 8];                         \
    f32x4 part = MFMA(wx0h, bxh0, biasC);   /* overlaps h-read/trans */        \
    f32x4 z = MFMA(whh_, bhh1, xzA);                                           \
    float iv = sigm(z[0]), fv = sigm(z[1]);                                    \
    float gv = 2.0f * sigm(z[2]) - 1.0f, ov = sigm(z[3]);                      \
    cc = fmaf(fv, cc, iv * gv);                                                \
    float hv = ov * tanh_f(cc);                                                \
    if (c16 < 8) hh[0][c16][jj] = bf16_rne(hv);                                \
    __syncthreads();   /* A: h[2td] visible */                                 \
    /* phase 2: rec step 2td+1 + XGEMM second half (covers h-read latency) */  \
    bf16x8 bxh1 = *(const bf16x8*)&xh[s1][c16][32 + kg * 8];                   \
    bf16x8 bhh0 = *(const bf16x8*)&hh[0][c16][kg * 8];                         \
    f32x4 xzA_n = MFMA(wx1h, bxh1, part);                                      \
    f32x4 xz1s_n;                                                              \
    _Pragma("unroll")                                                          \
    for (int r = 0; r < 4; ++r) xz1s_n[r] = __shfl_xor(xzA_n[r], 8);           \
    z = MFMA(whh_, bhh0, xz1s);                                                \
    iv = sigm(z[0]); fv = sigm(z[1]);                                          \
    gv = 2.0f * sigm(z[2]) - 1.0f; ov = sigm(z[3]);                            \
    cc = fmaf(fv, cc, iv * gv);                                                \
    hv = ov * tanh_f(cc);                                                      \
    if (c16 < 8) {                                                             \
        hh[1][c16][jj] = bf16_rne(hv);                                         \
        if (td == 255) Hd[0][c16][jj] = hv;                                    \
    }                                                                          \
    XV = xnext;                                                                \
    xzA = xzA_n; xz1s = xz1s_n;                                                \
    __syncthreads();   /* B: h[2td+1] + slot td+2 visible */                   \
}

    for (int qd = 0; qd < 128; ++qd) {
        DSTEP(2 * qd,     xvA)
        DSTEP(2 * qd + 1, xvB)
    }
#undef DSTEP

    __syncthreads();

    // ---- MLP head: 32 -> 32 -> 16 -> 3, leaky_relu(0.01) ----
    if (tid < 256) {
        int rb = tid >> 5, n = tid & 31;
        float a = b1[n];
#pragma unroll
        for (int k = 0; k < 32; ++k) a = fmaf(Hd[0][rb][k], W1[k * 32 + n], a);
        a = (a > 0.0f) ? a : 0.01f * a;
        Hd[1][rb][n] = a;
    }
    __syncthreads();
    if (tid < 128) {
        int rb = tid >> 4, n = tid & 15;
        float a = b2[n];
#pragma unroll
        for (int k = 0; k < 32; ++k) a = fmaf(Hd[1][rb][k], W2[k * 16 + n], a);
        a = (a > 0.0f) ? a : 0.01f * a;
        Hd[2][rb][n] = a;
    }
    __syncthreads();
    if (tid < 24) {
        int rb = tid / 3, n = tid - rb * 3;
        float a = bo[n];
#pragma unroll
        for (int k = 0; k < 16; ++k) a = fmaf(Hd[2][rb][k], Wo[k * 3 + n], a);
        out[(size_t)(bb + rb) * 3 + n] = a;
    }
}

extern "C" void kernel_launch(void* const* d_in, const int* in_sizes, int n_in,
                              void* d_out, int out_size, void* d_ws, size_t ws_size,
                              hipStream_t stream) {
    const float* x  = (const float*)d_in[0];
    const float* Wx = (const float*)d_in[1];
    const float* Wh = (const float*)d_in[2];
    const float* bg = (const float*)d_in[3];
    const float* W1 = (const float*)d_in[4];
    const float* b1 = (const float*)d_in[5];
    const float* W2 = (const float*)d_in[6];
    const float* b2 = (const float*)d_in[7];
    const float* Wo = (const float*)d_in[8];
    const float* bo = (const float*)d_in[9];
    float* out = (float*)d_out;

    hipLaunchKernelGGL(lstm_mfma_kernel, dim3(NB), dim3(512), 0, stream,
                       x, Wx, Wh, bg, W1, b1, W2, b2, Wo, bo, out);
}